// Round 9
// baseline (330.407 us; speedup 1.0000x reference)
//
#include <hip/hip_runtime.h>
#include <cstdint>
#include <cstddef>

#define NN 250000   // nodes
#define FF 256      // channels
#define GG 4096     // graphs
#define TT 6        // processing steps

typedef _Float16 half8_t __attribute__((ext_vector_type(8)));
typedef _Float16 half4_t __attribute__((ext_vector_type(4)));
typedef _Float16 half2_t __attribute__((ext_vector_type(2)));
typedef float f32x4 __attribute__((ext_vector_type(4)));

__device__ __forceinline__ float fdot2f(half2_t a, half2_t b, float c) {
#if __has_builtin(__builtin_amdgcn_fdot2)
  return __builtin_amdgcn_fdot2(a, b, c, false);
#else
  return c + (float)a[0] * (float)b[0] + (float)a[1] * (float)b[1];
#endif
}

__device__ __forceinline__ float dot8(half8_t x, half8_t q) {
  float d = fdot2f((half2_t){x[0], x[1]}, (half2_t){q[0], q[1]}, 0.f);
  d = fdot2f((half2_t){x[2], x[3]}, (half2_t){q[2], q[3]}, d);
  d = fdot2f((half2_t){x[4], x[5]}, (half2_t){q[4], q[5]}, d);
  d = fdot2f((half2_t){x[6], x[7]}, (half2_t){q[6], q[7]}, d);
  return d;
}

// ---------------- t=0: fused prep + bias-LSTM + f32 sweep + x16 mirror ----------------
// Block g: computes its own starts (2 binary searches) and publishes starts[g];
// blocks < 512 also build 1024 elements of w16 each (512*1024 = 524288 = |w16|).
// Sweep: 1 node per wave, manual 4-node groups -> 4 NT loads in flight.
__global__ __launch_bounds__(256) void attn0_kernel(
    const float* __restrict__ x32, const int* __restrict__ batch,
    const float* __restrict__ Wih, const float* __restrict__ Whh,
    const float* __restrict__ bih, const float* __restrict__ bhh,
    _Float16* __restrict__ w16, int* __restrict__ starts,
    float* __restrict__ c, _Float16* __restrict__ x16w,
    _Float16* __restrict__ q16out) {
  int g = blockIdx.x, tid = threadIdx.x, lane = tid & 63, w = tid >> 6;
  __shared__ int sgs[2];
  __shared__ __align__(16) float h_sh[FF];
  __shared__ __align__(16) float rw[4][FF];
  __shared__ float mw[4], sw[4];

  if (tid < 2) {
    int target = g + tid;
    int lo = 0;
    if (target >= GG) lo = NN;
    else {
      int hi = NN;
      while (lo < hi) {
        int mid = (lo + hi) >> 1;
        if (batch[mid] < target) lo = mid + 1; else hi = mid;
      }
    }
    sgs[tid] = lo;
    starts[g + tid] = lo;
  }

  // w16 prep: blocks 0..511 x 1024 elements = 524288 exactly.
  if (g < 512) {
#pragma unroll
    for (int e = 0; e < 4; ++e) {
      int idx = g * 1024 + e * 256 + tid;
      int j = idx >> 9, k = idx & 511;
      float v = Wih[(size_t)j * 512 + k];
      if (k < FF) v += Whh[(size_t)j * FF + k];
      w16[idx] = (_Float16)v;
    }
  }

  // t0 LSTM: gates = bias only (q_star = h = c = 0); identical for all graphs
  float bi = bih[tid] + bhh[tid];
  float bg = bih[tid + 512] + bhh[tid + 512];
  float bo = bih[tid + 768] + bhh[tid + 768];
  float si0 = 1.f / (1.f + __expf(-bi));
  float so0 = 1.f / (1.f + __expf(-bo));
  float cv0 = si0 * tanhf(bg);
  float hv0 = so0 * tanhf(cv0);
  c[(size_t)g * FF + tid] = cv0;
  q16out[(size_t)g * 512 + tid] = (_Float16)hv0;  // h half for t1 gemm
  h_sh[tid] = hv0;
  __syncthreads();

  f32x4 qv = *(const f32x4*)&h_sh[4 * lane];
  int s0 = sgs[0], cnt = sgs[1] - sgs[0];

  float m = -INFINITY, ssum = 0.f;
  f32x4 racc = {0.f, 0.f, 0.f, 0.f};
  for (int i0 = w * 4; i0 < cnt; i0 += 16) {
    f32x4 xv[4];
    float d[4];
    bool vld[4];
#pragma unroll
    for (int j = 0; j < 4; ++j) {              // 4 x 1 KB loads in flight
      int idx = i0 + j;
      vld[j] = idx < cnt;
      int node = vld[j] ? idx : cnt - 1;
      xv[j] = __builtin_nontemporal_load(
          (const f32x4*)(x32 + (size_t)(s0 + node) * FF + 4 * lane));
    }
#pragma unroll
    for (int j = 0; j < 4; ++j) {              // x16 mirror (dup-clamped ok)
      half4_t hx;
      hx[0] = (_Float16)xv[j][0]; hx[1] = (_Float16)xv[j][1];
      hx[2] = (_Float16)xv[j][2]; hx[3] = (_Float16)xv[j][3];
      int node = vld[j] ? (i0 + j) : cnt - 1;
      *(half4_t*)(x16w + (size_t)(s0 + node) * FF + 4 * lane) = hx;
    }
#pragma unroll
    for (int j = 0; j < 4; ++j)
      d[j] = xv[j][0] * qv[0] + xv[j][1] * qv[1] + xv[j][2] * qv[2] + xv[j][3] * qv[3];
#pragma unroll
    for (int off = 32; off; off >>= 1)         // 4 interleaved trees
#pragma unroll
      for (int j = 0; j < 4; ++j) d[j] += __shfl_xor(d[j], off);
#pragma unroll
    for (int j = 0; j < 4; ++j) if (!vld[j]) d[j] = -INFINITY;
    float gm = fmaxf(fmaxf(d[0], d[1]), fmaxf(d[2], d[3]));
    if (gm > m) {                              // wave-uniform, one per 4 nodes
      float sc = __expf(m - gm);
      ssum *= sc; racc *= sc;
      m = gm;
    }
#pragma unroll
    for (int j = 0; j < 4; ++j) {
      float p = __expf(d[j] - m);              // invalid: exp(-inf)=0
      ssum += p;
      racc += p * xv[j];
    }
  }

  if (lane == 0) { mw[w] = m; sw[w] = ssum; }
  *(f32x4*)&rw[w][4 * lane] = racc;
  __syncthreads();
  float M = fmaxf(fmaxf(mw[0], mw[1]), fmaxf(mw[2], mw[3]));
  float e0 = (mw[0] == -INFINITY) ? 0.f : __expf(mw[0] - M);
  float e1 = (mw[1] == -INFINITY) ? 0.f : __expf(mw[1] - M);
  float e2 = (mw[2] == -INFINITY) ? 0.f : __expf(mw[2] - M);
  float e3 = (mw[3] == -INFINITY) ? 0.f : __expf(mw[3] - M);
  float denom = sw[0] * e0 + sw[1] * e1 + sw[2] * e2 + sw[3] * e3;
  float rs = rw[0][tid] * e0 + rw[1][tid] * e1 + rw[2][tid] * e2 + rw[3][tid] * e3;
  float r = rs / (denom + 1e-16f);
  if (cnt == 0) r = 0.f;
  q16out[(size_t)g * 512 + FF + tid] = (_Float16)r;  // r half for t1 gemm
}

// ---------------- fused gates-GEMM + LSTM pointwise ----------------
// Block: 64 graphs x 32 f; W-cols {f, f+256, f+512, f+768}. Grid (64, 8).
template <bool LAST>
__global__ __launch_bounds__(256) void gemm_lstm_kernel(
    const _Float16* __restrict__ q16in, const _Float16* __restrict__ w16,
    const float* __restrict__ bih, const float* __restrict__ bhh,
    float* __restrict__ c, float* __restrict__ qstar,
    _Float16* __restrict__ q16out) {
  int lane = threadIdx.x & 63;
  int w    = threadIdx.x >> 6;
  int wm = w >> 1, wn = w & 1;
  int g0 = blockIdx.x * 64 + wm * 32;
  int f0 = blockIdx.y * 32 + wn * 16;
  int lr = lane & 15, kq = lane >> 4;

  f32x4 acc[2][4];
#pragma unroll
  for (int m = 0; m < 2; ++m)
#pragma unroll
    for (int gt = 0; gt < 4; ++gt) acc[m][gt] = (f32x4){0.f, 0.f, 0.f, 0.f};

#pragma unroll 4
  for (int k0 = 0; k0 < 512; k0 += 32) {
    int kk = k0 + kq * 8;
    half8_t a[2], b[4];
#pragma unroll
    for (int m = 0; m < 2; ++m)
      a[m] = *(const half8_t*)(q16in + (size_t)(g0 + m * 16 + lr) * 512 + kk);
#pragma unroll
    for (int gt = 0; gt < 4; ++gt)
      b[gt] = *(const half8_t*)(w16 + (size_t)(gt * 256 + f0 + lr) * 512 + kk);
#pragma unroll
    for (int m = 0; m < 2; ++m)
#pragma unroll
      for (int gt = 0; gt < 4; ++gt)
        acc[m][gt] = __builtin_amdgcn_mfma_f32_16x16x32_f16(a[m], b[gt], acc[m][gt], 0, 0, 0);
  }

  int f = f0 + lr;
  float bi  = bih[f]       + bhh[f];
  float bf2 = bih[f + 256] + bhh[f + 256];
  float bg  = bih[f + 512] + bhh[f + 512];
  float bo  = bih[f + 768] + bhh[f + 768];
#pragma unroll
  for (int m = 0; m < 2; ++m)
#pragma unroll
    for (int r = 0; r < 4; ++r) {
      int g = g0 + m * 16 + kq * 4 + r;
      float ig = acc[m][0][r] + bi;
      float fg = acc[m][1][r] + bf2;
      float gv = acc[m][2][r] + bg;
      float og = acc[m][3][r] + bo;
      float si = 1.f / (1.f + __expf(-ig));
      float sf = 1.f / (1.f + __expf(-fg));
      float so = 1.f / (1.f + __expf(-og));
      size_t ci = (size_t)g * FF + f;
      float cv = sf * c[ci] + si * tanhf(gv);
      float hv = so * tanhf(cv);
      c[ci] = cv;
      if (LAST) qstar[(size_t)g * 512 + f] = hv;
      q16out[(size_t)g * 512 + f] = (_Float16)hv;
    }
}

// ---------------- t>=1 attention: f16, 2 nodes/wave, 16-node groups ----------------
// Per iteration a wave loads 8 half8 tiles (16 nodes across its two 32-lane
// halves) BEFORE any reduction: 8 loads (8 KB) in flight, 8 interleaved
// shuffle trees, one rescale check per 16 nodes.
template <bool LAST>
__global__ __launch_bounds__(256) void attn_kernel(
    const _Float16* __restrict__ x16, const int* __restrict__ starts,
    float* __restrict__ qstar, _Float16* __restrict__ q16) {
  int g = blockIdx.x, tid = threadIdx.x, lane = tid & 63, w = tid >> 6;
  int sl = lane & 31, hf = lane >> 5;
  __shared__ __align__(16) float rw[4][FF];
  __shared__ float mw[4], sw[4];

  int s0 = starts[g];
  int cnt = starts[g + 1] - s0;
  half8_t qh = *(const half8_t*)(q16 + (size_t)g * 512 + sl * 8);

  float m = -INFINITY, ssum = 0.f;
  float racc[8];
#pragma unroll
  for (int e = 0; e < 8; ++e) racc[e] = 0.f;

  for (int i0 = w * 2; i0 < cnt; i0 += 64) {
    half8_t hx[8];
    float d[8];
    bool vld[8];
#pragma unroll
    for (int j = 0; j < 8; ++j) {              // 8 x 1 KB loads in flight
      int idx = i0 + j * 8 + hf;
      vld[j] = idx < cnt;
      int node = vld[j] ? idx : cnt - 1;
      hx[j] = *(const half8_t*)(x16 + (size_t)(s0 + node) * FF + sl * 8);
    }
#pragma unroll
    for (int j = 0; j < 8; ++j) d[j] = dot8(hx[j], qh);
#pragma unroll
    for (int off = 1; off <= 16; off <<= 1)    // 8 interleaved trees
#pragma unroll
      for (int j = 0; j < 8; ++j) d[j] += __shfl_xor(d[j], off);
#pragma unroll
    for (int j = 0; j < 8; ++j) if (!vld[j]) d[j] = -INFINITY;
    float gm = -INFINITY;
#pragma unroll
    for (int j = 0; j < 8; ++j) {
      float dother = __shfl_xor(d[j], 32);
      gm = fmaxf(gm, fmaxf(d[j], dother));     // uniform across the wave
    }
    if (gm > m) {                              // one rescale per 16 nodes
      float sc = __expf(m - gm);
      ssum *= sc;
#pragma unroll
      for (int e = 0; e < 8; ++e) racc[e] *= sc;
      m = gm;
    }
#pragma unroll
    for (int j = 0; j < 8; ++j) {
      float p = __expf(d[j] - m);              // invalid: exp(-inf)=0
      ssum += p;
#pragma unroll
      for (int e = 0; e < 8; ++e) racc[e] += p * (float)hx[j][e];
    }
  }

  // combine the two 32-lane halves of each wave
  ssum += __shfl_xor(ssum, 32);
#pragma unroll
  for (int e = 0; e < 8; ++e) racc[e] += __shfl_xor(racc[e], 32);

  if (lane == 0) { mw[w] = m; sw[w] = ssum; }
  if (hf == 0) {
    f32x4 lo = {racc[0], racc[1], racc[2], racc[3]};
    f32x4 hi = {racc[4], racc[5], racc[6], racc[7]};
    *(f32x4*)&rw[w][sl * 8] = lo;
    *(f32x4*)&rw[w][sl * 8 + 4] = hi;
  }
  __syncthreads();

  float M = fmaxf(fmaxf(mw[0], mw[1]), fmaxf(mw[2], mw[3]));
  float e0 = (mw[0] == -INFINITY) ? 0.f : __expf(mw[0] - M);
  float e1 = (mw[1] == -INFINITY) ? 0.f : __expf(mw[1] - M);
  float e2 = (mw[2] == -INFINITY) ? 0.f : __expf(mw[2] - M);
  float e3 = (mw[3] == -INFINITY) ? 0.f : __expf(mw[3] - M);
  float denom = sw[0] * e0 + sw[1] * e1 + sw[2] * e2 + sw[3] * e3;
  float rs = rw[0][tid] * e0 + rw[1][tid] * e1 + rw[2][tid] * e2 + rw[3][tid] * e3;
  float r = rs / (denom + 1e-16f);
  if (cnt == 0) r = 0.f;
  if (LAST) qstar[(size_t)g * 512 + FF + tid] = r;
  else      q16[(size_t)g * 512 + FF + tid] = (_Float16)r;
}

// ---------------- launcher ----------------
extern "C" void kernel_launch(void* const* d_in, const int* in_sizes, int n_in,
                              void* d_out, int out_size, void* d_ws, size_t ws_size,
                              hipStream_t stream) {
  const float* x   = (const float*)d_in[0];
  const int* batch = (const int*)d_in[1];
  // d_in[2] = size (4096), hard-coded
  const float* Wih = (const float*)d_in[3];
  const float* Whh = (const float*)d_in[4];
  const float* bih = (const float*)d_in[5];
  const float* bhh = (const float*)d_in[6];
  float* qstar = (float*)d_out;  // [GG, 512]; final step writes it

  uint8_t* p = (uint8_t*)d_ws;
  auto alloc = [&](size_t bytes) {
    uint8_t* q = p;
    p += (bytes + 255) & ~(size_t)255;
    return q;
  };
  float* c_st    = (float*)alloc((size_t)GG * FF * 4);            // 4 MB
  _Float16* q16a = (_Float16*)alloc((size_t)GG * 2 * FF * 2);     // 4 MB
  _Float16* q16b = (_Float16*)alloc((size_t)GG * 2 * FF * 2);     // 4 MB
  _Float16* w16  = (_Float16*)alloc((size_t)4 * FF * 2 * FF * 2); // 1 MB
  int* starts    = (int*)alloc((size_t)(GG + 1) * 4);
  _Float16* x16  = (_Float16*)alloc((size_t)NN * FF * 2);         // 128 MB

  attn0_kernel<<<GG, 256, 0, stream>>>(
      x, batch, Wih, Whh, bih, bhh, w16, starts, c_st, x16, q16a);

  for (int t = 1; t < TT; ++t) {
    _Float16* qin  = (t & 1) ? q16a : q16b;
    _Float16* qout = (t & 1) ? q16b : q16a;
    if (t < TT - 1) {
      gemm_lstm_kernel<false><<<dim3(64, 8), 256, 0, stream>>>(
          qin, w16, bih, bhh, c_st, qstar, qout);
      attn_kernel<false><<<GG, 256, 0, stream>>>(x16, starts, qstar, qout);
    } else {
      gemm_lstm_kernel<true><<<dim3(64, 8), 256, 0, stream>>>(
          qin, w16, bih, bhh, c_st, qstar, qout);
      attn_kernel<true><<<GG, 256, 0, stream>>>(x16, starts, qstar, qout);
    }
  }
}

// Round 10
// 282.999 us; speedup vs baseline: 1.1675x; 1.1675x over previous
//
#include <hip/hip_runtime.h>
#include <cstdint>
#include <cstddef>

#define NN 250000   // nodes
#define FF 256      // channels
#define GG 4096     // graphs
#define TT 6        // processing steps
#define GPB 16      // graphs per block in steps_kernel
#define SBLK (GG / GPB)   // 256 blocks = 1/CU

typedef _Float16 half8_t __attribute__((ext_vector_type(8)));
typedef _Float16 half4_t __attribute__((ext_vector_type(4)));
typedef _Float16 half2_t __attribute__((ext_vector_type(2)));
typedef float f32x4 __attribute__((ext_vector_type(4)));

__device__ __forceinline__ float fdot2f(half2_t a, half2_t b, float c) {
#if __has_builtin(__builtin_amdgcn_fdot2)
  return __builtin_amdgcn_fdot2(a, b, c, false);
#else
  return c + (float)a[0] * (float)b[0] + (float)a[1] * (float)b[1];
#endif
}

__device__ __forceinline__ float dot8(half8_t x, half8_t q) {
  float d = fdot2f((half2_t){x[0], x[1]}, (half2_t){q[0], q[1]}, 0.f);
  d = fdot2f((half2_t){x[2], x[3]}, (half2_t){q[2], q[3]}, d);
  d = fdot2f((half2_t){x[4], x[5]}, (half2_t){q[4], q[5]}, d);
  d = fdot2f((half2_t){x[6], x[7]}, (half2_t){q[6], q[7]}, d);
  return d;
}

// ---------------- t=0: fused prep + bias-LSTM + f32 sweep + x16 mirror ----------------
// Also builds the FRAGMENT-MAJOR swizzled weight matrix w16f:
//   tile (nf, ks) covers W rows nf*16..+16, k ks*32..+32; stored as 64 lanes x half8
//   element (n,k) -> w16f[(nf*16+ks)*512 + kq*128 + nr*8 + j]
//   (nf=n>>4, nr=n&15, ks=k>>5, kq=(k>>3)&3, j=k&7) so a wave's B-frag load is
//   one coalesced 1 KB burst: half8 at (nf*16+ks)*512 + lane*8.
__global__ __launch_bounds__(256) void attn0_kernel(
    const float* __restrict__ x32, const int* __restrict__ batch,
    const float* __restrict__ Wih, const float* __restrict__ Whh,
    const float* __restrict__ bih, const float* __restrict__ bhh,
    _Float16* __restrict__ w16f, int* __restrict__ starts,
    _Float16* __restrict__ x16w, _Float16* __restrict__ q16out) {
  int g = blockIdx.x, tid = threadIdx.x, lane = tid & 63, w = tid >> 6;
  __shared__ int sgs[2];
  __shared__ __align__(16) float h_sh[FF];
  __shared__ __align__(16) float rw[4][FF];
  __shared__ float mw[4], sw[4];

  if (tid < 2) {
    int target = g + tid;
    int lo = 0;
    if (target >= GG) lo = NN;
    else {
      int hi = NN;
      while (lo < hi) {
        int mid = (lo + hi) >> 1;
        if (batch[mid] < target) lo = mid + 1; else hi = mid;
      }
    }
    sgs[tid] = lo;
    starts[g + tid] = lo;
  }

  // w16f prep: blocks 0..511 x 1024 elements = 524288 exactly.
  if (g < 512) {
#pragma unroll
    for (int e = 0; e < 4; ++e) {
      int idx = g * 1024 + e * 256 + tid;
      int n = idx >> 9, k = idx & 511;
      float v = Wih[(size_t)n * 512 + k];
      if (k < FF) v += Whh[(size_t)n * FF + k];
      int dest = ((n >> 4) * 16 + (k >> 5)) * 512 + ((k >> 3) & 3) * 128 +
                 (n & 15) * 8 + (k & 7);
      w16f[dest] = (_Float16)v;
    }
  }

  // t0 LSTM: gates = bias only (q_star = h = c = 0); identical for all graphs
  float bi = bih[tid] + bhh[tid];
  float bg = bih[tid + 512] + bhh[tid + 512];
  float bo = bih[tid + 768] + bhh[tid + 768];
  float si0 = 1.f / (1.f + __expf(-bi));
  float so0 = 1.f / (1.f + __expf(-bo));
  float cv0 = si0 * tanhf(bg);
  float hv0 = so0 * tanhf(cv0);
  q16out[(size_t)g * 512 + tid] = (_Float16)hv0;  // h half for t1 gemm
  h_sh[tid] = hv0;
  __syncthreads();

  f32x4 qv = *(const f32x4*)&h_sh[4 * lane];
  int s0 = sgs[0], cnt = sgs[1] - sgs[0];

  float m = -INFINITY, ssum = 0.f;
  f32x4 racc = {0.f, 0.f, 0.f, 0.f};
  for (int i0 = w * 4; i0 < cnt; i0 += 16) {
    f32x4 xv[4];
    float d[4];
    bool vld[4];
#pragma unroll
    for (int j = 0; j < 4; ++j) {              // 4 x 1 KB NT loads in flight
      int idx = i0 + j;
      vld[j] = idx < cnt;
      int node = vld[j] ? idx : cnt - 1;
      xv[j] = __builtin_nontemporal_load(
          (const f32x4*)(x32 + (size_t)(s0 + node) * FF + 4 * lane));
    }
#pragma unroll
    for (int j = 0; j < 4; ++j) {              // x16 mirror (dup-clamped ok)
      half4_t hx;
      hx[0] = (_Float16)xv[j][0]; hx[1] = (_Float16)xv[j][1];
      hx[2] = (_Float16)xv[j][2]; hx[3] = (_Float16)xv[j][3];
      int node = vld[j] ? (i0 + j) : cnt - 1;
      *(half4_t*)(x16w + (size_t)(s0 + node) * FF + 4 * lane) = hx;
    }
#pragma unroll
    for (int j = 0; j < 4; ++j)
      d[j] = xv[j][0] * qv[0] + xv[j][1] * qv[1] + xv[j][2] * qv[2] + xv[j][3] * qv[3];
#pragma unroll
    for (int off = 32; off; off >>= 1)
#pragma unroll
      for (int j = 0; j < 4; ++j) d[j] += __shfl_xor(d[j], off);
#pragma unroll
    for (int j = 0; j < 4; ++j) if (!vld[j]) d[j] = -INFINITY;
    float gm = fmaxf(fmaxf(d[0], d[1]), fmaxf(d[2], d[3]));
    if (gm > m) {                              // wave-uniform
      float sc = __expf(m - gm);
      ssum *= sc; racc *= sc;
      m = gm;
    }
#pragma unroll
    for (int j = 0; j < 4; ++j) {
      float p = __expf(d[j] - m);              // invalid: exp(-inf)=0
      ssum += p;
      racc += p * xv[j];
    }
  }

  if (lane == 0) { mw[w] = m; sw[w] = ssum; }
  *(f32x4*)&rw[w][4 * lane] = racc;
  __syncthreads();
  float M = fmaxf(fmaxf(mw[0], mw[1]), fmaxf(mw[2], mw[3]));
  float e0 = (mw[0] == -INFINITY) ? 0.f : __expf(mw[0] - M);
  float e1 = (mw[1] == -INFINITY) ? 0.f : __expf(mw[1] - M);
  float e2 = (mw[2] == -INFINITY) ? 0.f : __expf(mw[2] - M);
  float e3 = (mw[3] == -INFINITY) ? 0.f : __expf(mw[3] - M);
  float denom = sw[0] * e0 + sw[1] * e1 + sw[2] * e2 + sw[3] * e3;
  float rs = rw[0][tid] * e0 + rw[1][tid] * e1 + rw[2][tid] * e2 + rw[3][tid] * e3;
  float r = rs / (denom + 1e-16f);
  if (cnt == 0) r = 0.f;
  q16out[(size_t)g * 512 + FF + tid] = (_Float16)r;  // r half for t1 gemm
}

// ---------------- t=1..5: ALL remaining steps, no grid sync ----------------
// 256 blocks x 256 threads; block owns graphs [b*16, b*16+16) for all steps.
// q_star (f16) and c (f32) live in LDS the whole time.
// Per step: MFMA gemm (A from LDS, B = w16f coalesced) -> in-register LSTM
// pointwise -> wave-per-graph online-softmax attention over x16.
__global__ __launch_bounds__(256, 1) void steps_kernel(
    const _Float16* __restrict__ x16, const _Float16* __restrict__ w16f,
    const _Float16* __restrict__ q16a, const int* __restrict__ starts,
    const float* __restrict__ bih, const float* __restrict__ bhh,
    float* __restrict__ qstar) {
  int tid = threadIdx.x, lane = tid & 63, w = tid >> 6;
  int lr = lane & 15, kq = lane >> 4;     // gemm quarter coords
  int sl = lane & 31, hf = lane >> 5;     // attn half coords
  int g0 = blockIdx.x * GPB;

  __shared__ _Float16 qs[GPB][520];       // q_star rows (520 = 512 + 8 pad)
  __shared__ float cst[GPB][256];         // LSTM cell state
  __shared__ int sgs[GPB + 1];

  // ---- init: starts, q_star from attn0's q16a, c0 (bias-only) ----
  if (tid <= GPB) sgs[tid] = starts[g0 + tid];
#pragma unroll
  for (int e = 0; e < 4; ++e) {
    int chunk = e * 256 + tid;            // 16 rows x 64 half8 chunks
    int i = chunk >> 6, c8 = chunk & 63;
    *(half8_t*)&qs[i][c8 * 8] =
        *(const half8_t*)(q16a + (size_t)(g0 + i) * 512 + c8 * 8);
  }
  {
    float bi = bih[tid] + bhh[tid];
    float bg = bih[tid + 512] + bhh[tid + 512];
    float si0 = 1.f / (1.f + __expf(-bi));
    float cv0 = si0 * tanhf(bg);
    for (int i = 0; i < GPB; ++i) cst[i][tid] = cv0;
  }
  // pointwise biases: wave w owns f-cols [w*64, w*64+64), lane covers 4 fi
  int fo = w * 64;
  float bi_[4], bf_[4], bg_[4], bo_[4];
#pragma unroll
  for (int fi = 0; fi < 4; ++fi) {
    int f = fo + fi * 16 + lr;
    bi_[fi] = bih[f] + bhh[f];
    bf_[fi] = bih[f + 256] + bhh[f + 256];
    bg_[fi] = bih[f + 512] + bhh[f + 512];
    bo_[fi] = bih[f + 768] + bhh[f + 768];
  }
  __syncthreads();

  for (int t = 1; t < TT; ++t) {
    bool last = (t == TT - 1);

    // ---- gemm: 16 graphs x [fo..fo+64) x 4 gates, K = 512 ----
    f32x4 acc[4][4];                      // [fi][gate]
#pragma unroll
    for (int fi = 0; fi < 4; ++fi)
#pragma unroll
      for (int gt = 0; gt < 4; ++gt) acc[fi][gt] = (f32x4){0.f, 0.f, 0.f, 0.f};

#pragma unroll 2
    for (int ks = 0; ks < 16; ++ks) {
      int kk = ks * 32 + kq * 8;
      half8_t a = *(const half8_t*)&qs[lr][kk];   // A[graph=lr][k]
#pragma unroll
      for (int fi = 0; fi < 4; ++fi)
#pragma unroll
        for (int gt = 0; gt < 4; ++gt) {
          int nf = gt * 16 + (fo >> 4) + fi;      // W row-tile index
          half8_t b = *(const half8_t*)(
              w16f + ((size_t)nf * 16 + ks) * 512 + lane * 8);
          acc[fi][gt] = __builtin_amdgcn_mfma_f32_16x16x32_f16(a, b, acc[fi][gt], 0, 0, 0);
        }
    }
    __syncthreads();   // all waves done reading qs before h overwrite

    // ---- LSTM pointwise: lane holds all 4 gates of (graph kq*4+r, f) ----
#pragma unroll
    for (int fi = 0; fi < 4; ++fi) {
      int f = fo + fi * 16 + lr;
#pragma unroll
      for (int r = 0; r < 4; ++r) {
        int gl = kq * 4 + r;
        float ig = acc[fi][0][r] + bi_[fi];
        float fg = acc[fi][1][r] + bf_[fi];
        float gv = acc[fi][2][r] + bg_[fi];
        float og = acc[fi][3][r] + bo_[fi];
        float si = 1.f / (1.f + __expf(-ig));
        float sf = 1.f / (1.f + __expf(-fg));
        float so = 1.f / (1.f + __expf(-og));
        float cv = sf * cst[gl][f] + si * tanhf(gv);
        float hv = so * tanhf(cv);
        cst[gl][f] = cv;
        qs[gl][f] = (_Float16)hv;
        if (last) qstar[(size_t)(g0 + gl) * 512 + f] = hv;
      }
    }
    __syncthreads();   // full h rows visible before attn reads them

    // ---- attention: wave w owns graphs w, w+4, w+8, w+12 (no LDS merge) ----
    for (int ii = w; ii < GPB; ii += 4) {
      int s0 = sgs[ii];
      int cnt = sgs[ii + 1] - s0;
      half8_t qh = *(const half8_t*)&qs[ii][sl * 8];

      float m = -INFINITY, ssum = 0.f;
      float racc[8];
#pragma unroll
      for (int e = 0; e < 8; ++e) racc[e] = 0.f;

      for (int i0 = 0; i0 < cnt; i0 += 16) {     // 16 nodes/iter/wave
        half8_t hx[8];
        float d[8];
        bool vld[8];
#pragma unroll
        for (int j = 0; j < 8; ++j) {            // 8 x 1 KB loads in flight
          int idx = i0 + j * 2 + hf;
          vld[j] = idx < cnt;
          int node = vld[j] ? idx : cnt - 1;
          hx[j] = *(const half8_t*)(x16 + (size_t)(s0 + node) * FF + sl * 8);
        }
#pragma unroll
        for (int j = 0; j < 8; ++j) d[j] = dot8(hx[j], qh);
#pragma unroll
        for (int off = 1; off <= 16; off <<= 1)  // 8 interleaved 32-lane trees
#pragma unroll
          for (int j = 0; j < 8; ++j) d[j] += __shfl_xor(d[j], off);
#pragma unroll
        for (int j = 0; j < 8; ++j) if (!vld[j]) d[j] = -INFINITY;
        float gm = -INFINITY;
#pragma unroll
        for (int j = 0; j < 8; ++j) {
          float dother = __shfl_xor(d[j], 32);
          gm = fmaxf(gm, fmaxf(d[j], dother));   // uniform across wave
        }
        if (gm > m) {                            // one rescale per 16 nodes
          float sc = __expf(m - gm);
          ssum *= sc;
#pragma unroll
          for (int e = 0; e < 8; ++e) racc[e] *= sc;
          m = gm;
        }
#pragma unroll
        for (int j = 0; j < 8; ++j) {
          float p = __expf(d[j] - m);            // invalid: exp(-inf)=0
          ssum += p;
#pragma unroll
          for (int e = 0; e < 8; ++e) racc[e] += p * (float)hx[j][e];
        }
      }

      // combine the two 32-lane halves; then lane sl holds channels sl*8..+8
      ssum += __shfl_xor(ssum, 32);
#pragma unroll
      for (int e = 0; e < 8; ++e) racc[e] += __shfl_xor(racc[e], 32);
      float inv = 1.0f / (ssum + 1e-16f);

      if (hf == 0) {
        half8_t rh;
        float rv[8];
#pragma unroll
        for (int e = 0; e < 8; ++e) {
          rv[e] = (cnt == 0) ? 0.f : racc[e] * inv;
          rh[e] = (_Float16)rv[e];
        }
        *(half8_t*)&qs[ii][256 + sl * 8] = rh;   // r half for next gemm
        if (last) {
          f32x4 lo = {rv[0], rv[1], rv[2], rv[3]};
          f32x4 hi = {rv[4], rv[5], rv[6], rv[7]};
          *(f32x4*)(qstar + (size_t)(g0 + ii) * 512 + 256 + sl * 8) = lo;
          *(f32x4*)(qstar + (size_t)(g0 + ii) * 512 + 260 + sl * 8) = hi;
        }
      }
    }
    __syncthreads();   // r halves written before next step's gemm reads qs
  }
}

// ---------------- launcher ----------------
extern "C" void kernel_launch(void* const* d_in, const int* in_sizes, int n_in,
                              void* d_out, int out_size, void* d_ws, size_t ws_size,
                              hipStream_t stream) {
  const float* x   = (const float*)d_in[0];
  const int* batch = (const int*)d_in[1];
  // d_in[2] = size (4096), hard-coded
  const float* Wih = (const float*)d_in[3];
  const float* Whh = (const float*)d_in[4];
  const float* bih = (const float*)d_in[5];
  const float* bhh = (const float*)d_in[6];
  float* qstar = (float*)d_out;  // [GG, 512]; steps_kernel t=5 writes it

  uint8_t* p = (uint8_t*)d_ws;
  auto alloc = [&](size_t bytes) {
    uint8_t* q = p;
    p += (bytes + 255) & ~(size_t)255;
    return q;
  };
  _Float16* q16a = (_Float16*)alloc((size_t)GG * 2 * FF * 2);     // 4 MB
  _Float16* w16f = (_Float16*)alloc((size_t)4 * FF * 2 * FF * 2); // 1 MB
  int* starts    = (int*)alloc((size_t)(GG + 1) * 4);
  _Float16* x16  = (_Float16*)alloc((size_t)NN * FF * 2);         // 128 MB

  // t = 0: prep (starts + swizzled W) + bias-only LSTM + f32 sweep + x16 mirror
  attn0_kernel<<<GG, 256, 0, stream>>>(
      x, batch, Wih, Whh, bih, bhh, w16f, starts, x16, q16a);

  // t = 1..5 in one kernel, no grid sync (all per-graph work)
  steps_kernel<<<SBLK, 256, 0, stream>>>(
      x16, w16f, q16a, starts, bih, bhh, qstar);
}

// Round 11
// 242.560 us; speedup vs baseline: 1.3622x; 1.1667x over previous
//
#include <hip/hip_runtime.h>
#include <cstdint>
#include <cstddef>

#define NN 250000   // nodes
#define FF 256      // channels
#define GG 4096     // graphs
#define TT 6        // processing steps
#define GPB 16      // graphs per block in steps_kernel
#define SBLK (GG / GPB)   // 256 blocks

typedef _Float16 half8_t __attribute__((ext_vector_type(8)));
typedef _Float16 half4_t __attribute__((ext_vector_type(4)));
typedef _Float16 half2_t __attribute__((ext_vector_type(2)));
typedef float f32x4 __attribute__((ext_vector_type(4)));

__device__ __forceinline__ float fdot2f(half2_t a, half2_t b, float c) {
#if __has_builtin(__builtin_amdgcn_fdot2)
  return __builtin_amdgcn_fdot2(a, b, c, false);
#else
  return c + (float)a[0] * (float)b[0] + (float)a[1] * (float)b[1];
#endif
}

__device__ __forceinline__ float dot8(half8_t x, half8_t q) {
  float d = fdot2f((half2_t){x[0], x[1]}, (half2_t){q[0], q[1]}, 0.f);
  d = fdot2f((half2_t){x[2], x[3]}, (half2_t){q[2], q[3]}, d);
  d = fdot2f((half2_t){x[4], x[5]}, (half2_t){q[4], q[5]}, d);
  d = fdot2f((half2_t){x[6], x[7]}, (half2_t){q[6], q[7]}, d);
  return d;
}

// ---------------- t=0: fused prep + bias-LSTM + f32 sweep + x16 mirror ----------------
// Builds fragment-major w16f: element (n,k) -> w16f[((n>>4)*16 + (k>>5))*512 +
// ((k>>3)&3)*128 + (n&15)*8 + (k&7)] so a wave's B-frag load is one 1 KB burst.
__global__ __launch_bounds__(256) void attn0_kernel(
    const float* __restrict__ x32, const int* __restrict__ batch,
    const float* __restrict__ Wih, const float* __restrict__ Whh,
    const float* __restrict__ bih, const float* __restrict__ bhh,
    _Float16* __restrict__ w16f, int* __restrict__ starts,
    _Float16* __restrict__ x16w, _Float16* __restrict__ q16out) {
  int g = blockIdx.x, tid = threadIdx.x, lane = tid & 63, w = tid >> 6;
  __shared__ int sgs[2];
  __shared__ __align__(16) float h_sh[FF];
  __shared__ __align__(16) float rw[4][FF];
  __shared__ float mw[4], sw[4];

  if (tid < 2) {
    int target = g + tid;
    int lo = 0;
    if (target >= GG) lo = NN;
    else {
      int hi = NN;
      while (lo < hi) {
        int mid = (lo + hi) >> 1;
        if (batch[mid] < target) lo = mid + 1; else hi = mid;
      }
    }
    sgs[tid] = lo;
    starts[g + tid] = lo;
  }

  // w16f prep: blocks 0..511 x 1024 elements = 524288 exactly.
  if (g < 512) {
#pragma unroll
    for (int e = 0; e < 4; ++e) {
      int idx = g * 1024 + e * 256 + tid;
      int n = idx >> 9, k = idx & 511;
      float v = Wih[(size_t)n * 512 + k];
      if (k < FF) v += Whh[(size_t)n * FF + k];
      int dest = ((n >> 4) * 16 + (k >> 5)) * 512 + ((k >> 3) & 3) * 128 +
                 (n & 15) * 8 + (k & 7);
      w16f[dest] = (_Float16)v;
    }
  }

  // t0 LSTM: gates = bias only (q_star = h = c = 0); identical for all graphs
  float bi = bih[tid] + bhh[tid];
  float bg = bih[tid + 512] + bhh[tid + 512];
  float bo = bih[tid + 768] + bhh[tid + 768];
  float si0 = 1.f / (1.f + __expf(-bi));
  float so0 = 1.f / (1.f + __expf(-bo));
  float cv0 = si0 * tanhf(bg);
  float hv0 = so0 * tanhf(cv0);
  q16out[(size_t)g * 512 + tid] = (_Float16)hv0;  // h half for t1 gemm
  h_sh[tid] = hv0;
  __syncthreads();

  f32x4 qv = *(const f32x4*)&h_sh[4 * lane];
  int s0 = sgs[0], cnt = sgs[1] - sgs[0];

  float m = -INFINITY, ssum = 0.f;
  f32x4 racc = {0.f, 0.f, 0.f, 0.f};
  for (int i0 = w * 4; i0 < cnt; i0 += 16) {
    f32x4 xv[4];
    float d[4];
    bool vld[4];
#pragma unroll
    for (int j = 0; j < 4; ++j) {              // 4 x 1 KB NT loads in flight
      int idx = i0 + j;
      vld[j] = idx < cnt;
      int node = vld[j] ? idx : cnt - 1;
      xv[j] = __builtin_nontemporal_load(
          (const f32x4*)(x32 + (size_t)(s0 + node) * FF + 4 * lane));
    }
#pragma unroll
    for (int j = 0; j < 4; ++j) {              // x16 mirror (dup-clamped ok)
      half4_t hx;
      hx[0] = (_Float16)xv[j][0]; hx[1] = (_Float16)xv[j][1];
      hx[2] = (_Float16)xv[j][2]; hx[3] = (_Float16)xv[j][3];
      int node = vld[j] ? (i0 + j) : cnt - 1;
      *(half4_t*)(x16w + (size_t)(s0 + node) * FF + 4 * lane) = hx;
    }
#pragma unroll
    for (int j = 0; j < 4; ++j)
      d[j] = xv[j][0] * qv[0] + xv[j][1] * qv[1] + xv[j][2] * qv[2] + xv[j][3] * qv[3];
#pragma unroll
    for (int off = 32; off; off >>= 1)
#pragma unroll
      for (int j = 0; j < 4; ++j) d[j] += __shfl_xor(d[j], off);
#pragma unroll
    for (int j = 0; j < 4; ++j) if (!vld[j]) d[j] = -INFINITY;
    float gm = fmaxf(fmaxf(d[0], d[1]), fmaxf(d[2], d[3]));
    if (gm > m) {                              // wave-uniform
      float sc = __expf(m - gm);
      ssum *= sc; racc *= sc;
      m = gm;
    }
#pragma unroll
    for (int j = 0; j < 4; ++j) {
      float p = __expf(d[j] - m);              // invalid: exp(-inf)=0
      ssum += p;
      racc += p * xv[j];
    }
  }

  if (lane == 0) { mw[w] = m; sw[w] = ssum; }
  *(f32x4*)&rw[w][4 * lane] = racc;
  __syncthreads();
  float M = fmaxf(fmaxf(mw[0], mw[1]), fmaxf(mw[2], mw[3]));
  float e0 = (mw[0] == -INFINITY) ? 0.f : __expf(mw[0] - M);
  float e1 = (mw[1] == -INFINITY) ? 0.f : __expf(mw[1] - M);
  float e2 = (mw[2] == -INFINITY) ? 0.f : __expf(mw[2] - M);
  float e3 = (mw[3] == -INFINITY) ? 0.f : __expf(mw[3] - M);
  float denom = sw[0] * e0 + sw[1] * e1 + sw[2] * e2 + sw[3] * e3;
  float rs = rw[0][tid] * e0 + rw[1][tid] * e1 + rw[2][tid] * e2 + rw[3][tid] * e3;
  float r = rs / (denom + 1e-16f);
  if (cnt == 0) r = 0.f;
  q16out[(size_t)g * 512 + FF + tid] = (_Float16)r;  // r half for t1 gemm
}

// ---------------- t=1..5: all remaining steps, 8 waves/block ----------------
// 256 blocks x 512 threads (8 waves = 2/SIMD; R10's 4 waves = 1/SIMD was the
// latency-exposure bottleneck: VALUBusy 28%). Block owns graphs [b*16,b*16+16).
// q_star (f16) and c (f32) live in LDS across all steps.
__global__ __launch_bounds__(512, 1) void steps_kernel(
    const _Float16* __restrict__ x16, const _Float16* __restrict__ w16f,
    const _Float16* __restrict__ q16a, const int* __restrict__ starts,
    const float* __restrict__ bih, const float* __restrict__ bhh,
    float* __restrict__ qstar) {
  int tid = threadIdx.x, lane = tid & 63, w = tid >> 6;   // w in 0..7
  int lr = lane & 15, kq = lane >> 4;     // gemm quarter coords
  int sl = lane & 31, hf = lane >> 5;     // attn half coords
  int g0 = blockIdx.x * GPB;

  __shared__ _Float16 qs[GPB][520];       // q_star rows (520 = 512 + 8 pad)
  __shared__ float cst[GPB][256];         // LSTM cell state
  __shared__ int sgs[GPB + 1];

  // ---- init: starts, q_star from attn0, c0 (bias-only) ----
  if (tid <= GPB) sgs[tid] = starts[g0 + tid];
#pragma unroll
  for (int e = 0; e < 2; ++e) {           // 16 rows x 64 half8 = 1024 chunks
    int chunk = e * 512 + tid;
    int i = chunk >> 6, c8 = chunk & 63;
    *(half8_t*)&qs[i][c8 * 8] =
        *(const half8_t*)(q16a + (size_t)(g0 + i) * 512 + c8 * 8);
  }
  {
    int f = tid & 255;
    float bi = bih[f] + bhh[f];
    float bg = bih[f + 512] + bhh[f + 512];
    float si0 = 1.f / (1.f + __expf(-bi));
    float cv0 = si0 * tanhf(bg);
    for (int i = tid >> 8; i < GPB; i += 2) cst[i][f] = cv0;
  }
  // pointwise biases: wave w owns f-cols [w*32, w*32+32)
  int fo = w * 32;
  float bi_[2], bf_[2], bg_[2], bo_[2];
#pragma unroll
  for (int fi = 0; fi < 2; ++fi) {
    int f = fo + fi * 16 + lr;
    bi_[fi] = bih[f] + bhh[f];
    bf_[fi] = bih[f + 256] + bhh[f + 256];
    bg_[fi] = bih[f + 512] + bhh[f + 512];
    bo_[fi] = bih[f + 768] + bhh[f + 768];
  }
  __syncthreads();

  for (int t = 1; t < TT; ++t) {
    bool last = (t == TT - 1);

    // ---- gemm: 16 graphs x [fo..fo+32) x 4 gates, K = 512 ----
    f32x4 acc[2][4];                      // [fi][gate]
#pragma unroll
    for (int fi = 0; fi < 2; ++fi)
#pragma unroll
      for (int gt = 0; gt < 4; ++gt) acc[fi][gt] = (f32x4){0.f, 0.f, 0.f, 0.f};

#pragma unroll 2
    for (int ks = 0; ks < 16; ++ks) {
      int kk = ks * 32 + kq * 8;
      half8_t a = *(const half8_t*)&qs[lr][kk];   // A[graph=lr][k]
#pragma unroll
      for (int fi = 0; fi < 2; ++fi)
#pragma unroll
        for (int gt = 0; gt < 4; ++gt) {
          int nf = gt * 16 + w * 2 + fi;          // W row-tile index
          half8_t b = *(const half8_t*)(
              w16f + ((size_t)nf * 16 + ks) * 512 + lane * 8);
          acc[fi][gt] = __builtin_amdgcn_mfma_f32_16x16x32_f16(a, b, acc[fi][gt], 0, 0, 0);
        }
    }
    __syncthreads();   // all waves done reading qs before h overwrite

    // ---- LSTM pointwise: lane holds all 4 gates of (graph kq*4+r, f) ----
#pragma unroll
    for (int fi = 0; fi < 2; ++fi) {
      int f = fo + fi * 16 + lr;
#pragma unroll
      for (int r = 0; r < 4; ++r) {
        int gl = kq * 4 + r;
        float ig = acc[fi][0][r] + bi_[fi];
        float fg = acc[fi][1][r] + bf_[fi];
        float gv = acc[fi][2][r] + bg_[fi];
        float og = acc[fi][3][r] + bo_[fi];
        float si = 1.f / (1.f + __expf(-ig));
        float sf = 1.f / (1.f + __expf(-fg));
        float so = 1.f / (1.f + __expf(-og));
        float cv = sf * cst[gl][f] + si * tanhf(gv);
        float hv = so * tanhf(cv);
        cst[gl][f] = cv;
        qs[gl][f] = (_Float16)hv;
        if (last) qstar[(size_t)(g0 + gl) * 512 + f] = hv;
      }
    }
    __syncthreads();   // full h rows visible before attn reads them

    // ---- attention: wave w owns graphs w and w+8 ----
    for (int ii = w; ii < GPB; ii += 8) {
      int s0 = sgs[ii];
      int cnt = sgs[ii + 1] - s0;
      half8_t qh = *(const half8_t*)&qs[ii][sl * 8];

      float m = -INFINITY, ssum = 0.f;
      float racc[8];
#pragma unroll
      for (int e = 0; e < 8; ++e) racc[e] = 0.f;

      for (int i0 = 0; i0 < cnt; i0 += 16) {     // 16 nodes/iter/wave
        half8_t hx[8];
        float d[8];
        bool vld[8];
#pragma unroll
        for (int j = 0; j < 8; ++j) {            // 8 x 1 KB loads in flight
          int idx = i0 + j * 2 + hf;
          vld[j] = idx < cnt;
          int node = vld[j] ? idx : cnt - 1;
          hx[j] = *(const half8_t*)(x16 + (size_t)(s0 + node) * FF + sl * 8);
        }
#pragma unroll
        for (int j = 0; j < 8; ++j) d[j] = dot8(hx[j], qh);
#pragma unroll
        for (int off = 1; off <= 16; off <<= 1)  // 8 interleaved 32-lane trees
#pragma unroll
          for (int j = 0; j < 8; ++j) d[j] += __shfl_xor(d[j], off);
#pragma unroll
        for (int j = 0; j < 8; ++j) if (!vld[j]) d[j] = -INFINITY;
        float gm = -INFINITY;
#pragma unroll
        for (int j = 0; j < 8; ++j) {
          float dother = __shfl_xor(d[j], 32);
          gm = fmaxf(gm, fmaxf(d[j], dother));   // uniform across wave
        }
        if (gm > m) {                            // one rescale per 16 nodes
          float sc = __expf(m - gm);
          ssum *= sc;
#pragma unroll
          for (int e = 0; e < 8; ++e) racc[e] *= sc;
          m = gm;
        }
#pragma unroll
        for (int j = 0; j < 8; ++j) {
          float p = __expf(d[j] - m);            // invalid: exp(-inf)=0
          ssum += p;
#pragma unroll
          for (int e = 0; e < 8; ++e) racc[e] += p * (float)hx[j][e];
        }
      }

      // combine the two 32-lane halves; lane sl holds channels sl*8..+8
      ssum += __shfl_xor(ssum, 32);
#pragma unroll
      for (int e = 0; e < 8; ++e) racc[e] += __shfl_xor(racc[e], 32);
      float inv = 1.0f / (ssum + 1e-16f);

      if (hf == 0) {
        half8_t rh;
        float rv[8];
#pragma unroll
        for (int e = 0; e < 8; ++e) {
          rv[e] = (cnt == 0) ? 0.f : racc[e] * inv;
          rh[e] = (_Float16)rv[e];
        }
        *(half8_t*)&qs[ii][256 + sl * 8] = rh;   // r half for next gemm
        if (last) {
          f32x4 lo = {rv[0], rv[1], rv[2], rv[3]};
          f32x4 hi = {rv[4], rv[5], rv[6], rv[7]};
          *(f32x4*)(qstar + (size_t)(g0 + ii) * 512 + 256 + sl * 8) = lo;
          *(f32x4*)(qstar + (size_t)(g0 + ii) * 512 + 260 + sl * 8) = hi;
        }
      }
    }
    __syncthreads();   // r halves written before next step's gemm reads qs
  }
}

// ---------------- launcher ----------------
extern "C" void kernel_launch(void* const* d_in, const int* in_sizes, int n_in,
                              void* d_out, int out_size, void* d_ws, size_t ws_size,
                              hipStream_t stream) {
  const float* x   = (const float*)d_in[0];
  const int* batch = (const int*)d_in[1];
  // d_in[2] = size (4096), hard-coded
  const float* Wih = (const float*)d_in[3];
  const float* Whh = (const float*)d_in[4];
  const float* bih = (const float*)d_in[5];
  const float* bhh = (const float*)d_in[6];
  float* qstar = (float*)d_out;  // [GG, 512]; steps_kernel t=5 writes it

  uint8_t* p = (uint8_t*)d_ws;
  auto alloc = [&](size_t bytes) {
    uint8_t* q = p;
    p += (bytes + 255) & ~(size_t)255;
    return q;
  };
  _Float16* q16a = (_Float16*)alloc((size_t)GG * 2 * FF * 2);     // 4 MB
  _Float16* w16f = (_Float16*)alloc((size_t)4 * FF * 2 * FF * 2); // 1 MB
  int* starts    = (int*)alloc((size_t)(GG + 1) * 4);
  _Float16* x16  = (_Float16*)alloc((size_t)NN * FF * 2);         // 128 MB

  // t = 0: prep (starts + swizzled W) + bias-only LSTM + f32 sweep + x16 mirror
  attn0_kernel<<<GG, 256, 0, stream>>>(
      x, batch, Wih, Whh, bih, bhh, w16f, starts, x16, q16a);

  // t = 1..5 in one kernel, 8 waves/block
  steps_kernel<<<SBLK, 512, 0, stream>>>(
      x16, w16f, q16a, starts, bih, bhh, qstar);
}